// Round 1
// baseline (679.894 us; speedup 1.0000x reference)
//
#include <hip/hip_runtime.h>
#include <hip/hip_bf16.h>
#include <math.h>

#define B_ 16
#define S_ 2048
#define D_ 256
#define H_ 512
#define NS_ 64
#define N2 4096
#define M_ (B_*S_)

typedef float f32x4 __attribute__((ext_vector_type(4)));
typedef short bf16x8 __attribute__((ext_vector_type(8)));

__device__ __forceinline__ unsigned short f2bf(float x) {
    __hip_bfloat16 h = __float2bfloat16(x);
    return *reinterpret_cast<unsigned short*>(&h);
}

// ---------------- kernel 0: count zeros per batch ----------------
__global__ void count_kernel(const float* __restrict__ mask, int* __restrict__ cz) {
    int b = blockIdx.x;
    int t = threadIdx.x;
    float s = 0.0f;
    for (int j = t; j < S_; j += 256) s += 1.0f - mask[b*S_ + j];
    for (int off = 32; off; off >>= 1) s += __shfl_xor(s, off);
    __shared__ float red[4];
    if ((t & 63) == 0) red[t >> 6] = s;
    __syncthreads();
    if (t == 0) {
        float tot = red[0] + red[1] + red[2] + red[3];
        cz[b] = (int)(tot + 0.5f);
    }
}

// ---------------- kernel 1: W_glu (K,N) f32 -> Wt (N,K) bf16 ----------------
__global__ void wprep_kernel(const float* __restrict__ W, unsigned short* __restrict__ Wt) {
    int idx = blockIdx.x * 256 + threadIdx.x;   // idx = n*512 + k
    int n = idx >> 9, k = idx & 511;
    Wt[idx] = f2bf(W[k*H_ + n]);
}

// ---------------- kernel 2: per-channel kernel spectrum (bit-reversed DIF) ----------------
__global__ __launch_bounds__(256) void kfft_kernel(
        const float* __restrict__ log_dt, const float* __restrict__ log_A_real,
        const float* __restrict__ A_imag,
        const float* __restrict__ B_re, const float* __restrict__ B_im,
        const float* __restrict__ C_re, const float* __restrict__ C_im,
        float2* __restrict__ Kf) {
    int h = blockIdx.x, t = threadIdx.x;
    __shared__ float2 data[N2];
    __shared__ float2 tw[N2/2];
    __shared__ float lnr[NS_], ctr[NS_], cti[NS_];
    __shared__ double th[NS_];

    float dt = expf(log_dt[h]);
    if (t < NS_) {
        int n = t;
        float Ar = -expf(log_A_real[h*NS_ + n]);
        float Ai = A_imag[h*NS_ + n];
        float dr = 1.0f - 0.5f*dt*Ar, di = -0.5f*dt*Ai;   // 1 - dtA/2
        float nr = 1.0f + 0.5f*dt*Ar, ni =  0.5f*dt*Ai;   // 1 + dtA/2
        float den = dr*dr + di*di;
        float dAr = (nr*dr + ni*di) / den;
        float dAi = (ni*dr - nr*di) / den;
        float cr = C_re[h*NS_+n], ci = C_im[h*NS_+n];
        float br = B_re[h*NS_+n], bi = B_im[h*NS_+n];
        float pr = (cr*br - ci*bi) * dt, pi = (cr*bi + ci*br) * dt;
        float qr = (pr*dr + pi*di) / den;
        float qi = (pi*dr - pr*di) / den;
        lnr[n] = 0.5f * logf(dAr*dAr + dAi*dAi);
        th[n]  = atan2((double)dAi, (double)dAr);
        ctr[n] = qr; cti[n] = qi;
    }
    for (int j = t; j < N2/2; j += 256) {
        float a = (float)((double)j * (-6.283185307179586 / (double)N2));
        float sv, cv; sincosf(a, &sv, &cv);
        tw[j] = make_float2(cv, sv);
    }
    __syncthreads();

    const double TWO_PI = 6.283185307179586;
    for (int l = t; l < S_; l += 256) {
        float acc = 0.0f;
        for (int n = 0; n < NS_; ++n) {
            float mag = expf((float)l * lnr[n]);
            double ad = (double)l * th[n];
            ad -= floor(ad / TWO_PI + 0.5) * TWO_PI;
            float a = (float)ad;
            float sv, cv; sincosf(a, &sv, &cv);
            acc += ctr[n]*(mag*cv) - cti[n]*(mag*sv);
        }
        data[l] = make_float2(2.0f*acc, 0.0f);
    }
    for (int j = t + S_; j < N2; j += 256) data[j] = make_float2(0.0f, 0.0f);
    __syncthreads();

    // forward DIF (natural in -> bit-reversed out)
    for (int st = 11; st >= 0; --st) {
        int m = 1 << st;
        for (int j = t; j < N2/2; j += 256) {
            int pos = j & (m-1);
            int i0 = ((j >> st) << (st+1)) + pos, i1 = i0 + m;
            float2 a = data[i0], b = data[i1];
            float2 w = tw[pos << (11 - st)];
            float dx = a.x - b.x, dy = a.y - b.y;
            data[i0] = make_float2(a.x + b.x, a.y + b.y);
            data[i1] = make_float2(dx*w.x - dy*w.y, dx*w.y + dy*w.x);
        }
        __syncthreads();
    }
    const float scale = 1.0f / (float)N2;   // fold irfft 1/N here
    for (int j = t; j < N2; j += 256) {
        float2 v = data[j];
        Kf[(size_t)h*N2 + j] = make_float2(v.x*scale, v.y*scale);
    }
}

// ---------------- kernel 3: LayerNorm + build z_t (B,H,S) with reversed half ----------------
__global__ __launch_bounds__(256) void ln_kernel(
        const float* __restrict__ x, const float* __restrict__ gamma,
        const float* __restrict__ beta, const int* __restrict__ cz,
        float* __restrict__ z_t) {
    int blk = blockIdx.x;
    int b = blk >> 6;            // 64 s-tiles of 32 per batch
    int s0 = (blk & 63) * 32;
    int t = threadIdx.x;
    int lane = t & 63, wave = t >> 6;
    __shared__ float st[32][257];

    float4 g4  = *(const float4*)(gamma + lane*4);
    float4 be4 = *(const float4*)(beta  + lane*4);
    for (int q = 0; q < 8; ++q) {
        int row = wave*8 + q;
        int s = s0 + row;
        float4 v = *(const float4*)(x + ((size_t)(b*S_ + s))*D_ + lane*4);
        float sum = v.x + v.y + v.z + v.w;
        float ss  = v.x*v.x + v.y*v.y + v.z*v.z + v.w*v.w;
        for (int off = 32; off; off >>= 1) {
            sum += __shfl_xor(sum, off);
            ss  += __shfl_xor(ss, off);
        }
        float mean = sum * (1.0f/(float)D_);
        float var  = ss  * (1.0f/(float)D_) - mean*mean;
        float rstd = rsqrtf(var + 1e-5f);
        st[row][lane*4+0] = (v.x - mean)*rstd*g4.x + be4.x;
        st[row][lane*4+1] = (v.y - mean)*rstd*g4.y + be4.y;
        st[row][lane*4+2] = (v.z - mean)*rstd*g4.z + be4.z;
        st[row][lane*4+3] = (v.w - mean)*rstd*g4.w + be4.w;
    }
    __syncthreads();
    int czb = cz[b];
    int s_off = t & 31, dg = t >> 5;
    int s = s0 + s_off;
    int bs = (2*S_ - 1 - czb - s) % S_;
    for (int i = 0; i < 32; ++i) {
        int d = dg + 8*i;
        float v = st[s_off][d];
        z_t[((size_t)(b*H_ + d      ))*S_ + s ] = v;   // forward channel d
        z_t[((size_t)(b*H_ + D_ + d ))*S_ + bs] = v;   // reversed channel D+d
    }
}

// ---------------- kernel 4: FFT conv + D_skip + gelu, in place on z_t ----------------
__global__ __launch_bounds__(256) void fftconv_kernel(
        float* __restrict__ z_t, const float2* __restrict__ Kf,
        const float* __restrict__ D_skip) {
    int blk = blockIdx.x;
    int b = blk >> 9;      // H=512
    int h = blk & 511;
    int t = threadIdx.x;
    __shared__ float2 data[N2];
    __shared__ float2 tw[N2/2];

    float* zrow = z_t + ((size_t)(b*H_ + h))*S_;
    float zr[8];
    for (int j = 0; j < 8; ++j) {
        int s = t + 256*j;
        float v = zrow[s];
        zr[j] = v;
        data[s] = make_float2(v, 0.0f);
    }
    for (int j = t + S_; j < N2; j += 256) data[j] = make_float2(0.0f, 0.0f);
    for (int j = t; j < N2/2; j += 256) {
        float a = (float)((double)j * (-6.283185307179586 / (double)N2));
        float sv, cv; sincosf(a, &sv, &cv);
        tw[j] = make_float2(cv, sv);
    }
    __syncthreads();

    // forward DIF
    for (int st = 11; st >= 0; --st) {
        int m = 1 << st;
        for (int j = t; j < N2/2; j += 256) {
            int pos = j & (m-1);
            int i0 = ((j >> st) << (st+1)) + pos, i1 = i0 + m;
            float2 a = data[i0], bb = data[i1];
            float2 w = tw[pos << (11 - st)];
            float dx = a.x - bb.x, dy = a.y - bb.y;
            data[i0] = make_float2(a.x + bb.x, a.y + bb.y);
            data[i1] = make_float2(dx*w.x - dy*w.y, dx*w.y + dy*w.x);
        }
        __syncthreads();
    }
    // pointwise multiply with kernel spectrum (both bit-reversed)
    const float2* kfr = Kf + (size_t)h*N2;
    for (int j = t; j < N2; j += 256) {
        float2 v = data[j], k = kfr[j];
        data[j] = make_float2(v.x*k.x - v.y*k.y, v.x*k.y + v.y*k.x);
    }
    __syncthreads();
    // inverse DIT (bit-reversed in -> natural out), conjugate twiddles
    for (int st = 0; st <= 11; ++st) {
        int m = 1 << st;
        for (int j = t; j < N2/2; j += 256) {
            int pos = j & (m-1);
            int i0 = ((j >> st) << (st+1)) + pos, i1 = i0 + m;
            float2 w = tw[pos << (11 - st)];
            float2 a = data[i0], bb = data[i1];
            float tr = bb.x*w.x + bb.y*w.y;   // bb * conj(w)
            float ti = bb.y*w.x - bb.x*w.y;
            data[i0] = make_float2(a.x + tr, a.y + ti);
            data[i1] = make_float2(a.x - tr, a.y - ti);
        }
        __syncthreads();
    }
    float dsk = D_skip[h];
    for (int j = 0; j < 8; ++j) {
        int s = t + 256*j;
        float y = data[s].x + dsk * zr[j];
        float y3 = y*y*y;
        float g = 0.5f*y*(1.0f + tanhf(0.7978845608028654f*(y + 0.044715f*y3)));
        zrow[s] = g;
    }
}

// ---------------- kernel 5: (B,H,S) f32 -> (B,S,H) bf16 with back-half re-reversal ----------------
__global__ __launch_bounds__(256) void transpose_kernel(
        const float* __restrict__ y_t, const int* __restrict__ cz,
        unsigned short* __restrict__ A) {
    int b  = blockIdx.z;
    int h0 = blockIdx.y * 64;
    int s0 = blockIdx.x * 64;
    int t = threadIdx.x;
    int tx = t & 63, ty = t >> 6;
    __shared__ float tile[64][65];
    bool back = (h0 >= D_);
    int czb = cz[b];
    int s = s0 + tx;
    int scol = back ? ((2*S_ - 1 - czb - s) % S_) : s;
    for (int i = 0; i < 16; ++i) {
        int hh = ty*16 + i;
        tile[hh][tx] = y_t[((size_t)(b*H_ + h0 + hh))*S_ + scol];
    }
    __syncthreads();
    for (int i = 0; i < 16; ++i) {
        int sl = ty*16 + i;
        A[((size_t)(b*S_ + s0 + sl))*H_ + h0 + tx] = f2bf(tile[tx][sl]);
    }
}

// ---------------- kernel 6: GLU GEMM (MFMA bf16) + bias + sigmoid gate + residual ----------------
__global__ __launch_bounds__(256) void glu_gemm_kernel(
        const unsigned short* __restrict__ A, const unsigned short* __restrict__ Wt,
        const float* __restrict__ bglu, const float* __restrict__ x,
        float* __restrict__ out) {
    int m0 = blockIdx.x * 64;
    int n0 = blockIdx.y * 64;
    int t = threadIdx.x;
    int lane = t & 63, w = t >> 6;
    int wm = w & 1, wgrp = w >> 1;
    __shared__ __align__(16) short As[64][40];
    __shared__ __align__(16) short Bs[2][64][40];
    __shared__ float gs[64][132];

    f32x4 acc[2][4];
    for (int mf = 0; mf < 2; ++mf)
        for (int nf = 0; nf < 4; ++nf)
            acc[mf][nf] = (f32x4){0.0f, 0.0f, 0.0f, 0.0f};

    int srow = t >> 2;
    int scol = (t & 3) * 8;
    for (int kk = 0; kk < H_; kk += 32) {
        __syncthreads();
        *(int4*)&As[srow][scol]    = *(const int4*)(A  + ((size_t)(m0 + srow))*H_ + kk + scol);
        *(int4*)&Bs[0][srow][scol] = *(const int4*)(Wt + ((size_t)(n0 + srow))*H_ + kk + scol);
        *(int4*)&Bs[1][srow][scol] = *(const int4*)(Wt + ((size_t)(n0 + 256 + srow))*H_ + kk + scol);
        __syncthreads();
        int lr = lane & 15, ks = (lane >> 4) * 8;
        bf16x8 af[2], bf[4];
        for (int mf = 0; mf < 2; ++mf)
            af[mf] = *(bf16x8*)&As[wm*32 + mf*16 + lr][ks];
        for (int nf = 0; nf < 4; ++nf)
            bf[nf] = *(bf16x8*)&Bs[wgrp][nf*16 + lr][ks];
        for (int mf = 0; mf < 2; ++mf)
            for (int nf = 0; nf < 4; ++nf)
                acc[mf][nf] = __builtin_amdgcn_mfma_f32_16x16x32_bf16(af[mf], bf[nf], acc[mf][nf], 0, 0, 0);
    }
    __syncthreads();
    for (int mf = 0; mf < 2; ++mf)
        for (int nf = 0; nf < 4; ++nf)
            for (int r = 0; r < 4; ++r) {
                int row = wm*32 + mf*16 + (lane >> 4)*4 + r;
                int col = wgrp*64 + nf*16 + (lane & 15);
                gs[row][col] = acc[mf][nf][r];
            }
    __syncthreads();
    int col = t & 63;
    float ba = bglu[n0 + col], bb = bglu[n0 + 256 + col];
    for (int i = 0; i < 16; ++i) {
        int row = (t >> 6)*16 + i;
        size_t mr = (size_t)(m0 + row);
        float av = gs[row][col]      + ba;
        float bv = gs[row][64 + col] + bb;
        float sig = 1.0f / (1.0f + expf(-bv));
        out[mr*D_ + n0 + col] = av*sig + x[mr*D_ + n0 + col];
    }
}

// ---------------- launch ----------------
extern "C" void kernel_launch(void* const* d_in, const int* in_sizes, int n_in,
                              void* d_out, int out_size, void* d_ws, size_t ws_size,
                              hipStream_t stream) {
    const float* x         = (const float*)d_in[0];
    const float* mask      = (const float*)d_in[1];
    const float* log_dt    = (const float*)d_in[2];
    const float* log_A_real= (const float*)d_in[3];
    const float* A_imag    = (const float*)d_in[4];
    const float* B_re      = (const float*)d_in[5];
    const float* B_im      = (const float*)d_in[6];
    const float* C_re      = (const float*)d_in[7];
    const float* C_im      = (const float*)d_in[8];
    const float* D_skip    = (const float*)d_in[9];
    const float* W_glu     = (const float*)d_in[10];
    const float* b_glu     = (const float*)d_in[11];
    const float* ln_gamma  = (const float*)d_in[12];
    const float* ln_beta   = (const float*)d_in[13];
    float* out = (float*)d_out;

    char* ws = (char*)d_ws;
    // layout: cz(256B) | z_t 64MB | Kf 16MB | A_bf16 32MB | Wt 0.5MB  => ~112.5 MB
    int*            cz  = (int*)ws;
    float*          z_t = (float*)(ws + 256);
    float2*         Kf  = (float2*)(ws + 256 + 67108864);
    unsigned short* Abf = (unsigned short*)(ws + 256 + 67108864 + 16777216);
    unsigned short* Wt  = (unsigned short*)(ws + 256 + 67108864 + 16777216 + 33554432);

    count_kernel<<<B_, 256, 0, stream>>>(mask, cz);
    wprep_kernel<<<(H_*H_)/256, 256, 0, stream>>>(W_glu, Wt);
    kfft_kernel<<<H_, 256, 0, stream>>>(log_dt, log_A_real, A_imag, B_re, B_im, C_re, C_im, Kf);
    ln_kernel<<<B_*(S_/32), 256, 0, stream>>>(x, ln_gamma, ln_beta, cz, z_t);
    fftconv_kernel<<<B_*H_, 256, 0, stream>>>(z_t, Kf, D_skip);
    transpose_kernel<<<dim3(S_/64, H_/64, B_), 256, 0, stream>>>(z_t, cz, Abf);
    glu_gemm_kernel<<<dim3(M_/64, D_/64), 256, 0, stream>>>(Abf, Wt, b_glu, x, out);
}

// Round 2
// 536.687 us; speedup vs baseline: 1.2668x; 1.2668x over previous
//
#include <hip/hip_runtime.h>
#include <hip/hip_bf16.h>
#include <math.h>

#define B_ 16
#define S_ 2048
#define D_ 256
#define H_ 512
#define NS_ 64
#define N2 4096
#define M_ (B_*S_)
#define PD(i) ((i) + ((i) >> 5))

typedef float f32x4 __attribute__((ext_vector_type(4)));
typedef short bf16x8 __attribute__((ext_vector_type(8)));

__device__ __forceinline__ unsigned short f2bf(float x) {
    __hip_bfloat16 h = __float2bfloat16(x);
    return *reinterpret_cast<unsigned short*>(&h);
}

// base-4 digit reversal of a 12-bit index
__device__ __forceinline__ int dr4(int x) {
    unsigned r = __brev((unsigned)x) >> 20;
    return (int)(((r & 0x555u) << 1) | ((r >> 1) & 0x555u));
}

__device__ __forceinline__ float gelu_f(float y) {
    float u = y + 0.044715f*y*y*y;
    // 0.5*(1+tanh(0.79788456*u)) == 1/(1+exp2(-2.3022082*u)); safe at both extremes
    return y / (1.0f + __builtin_exp2f(-2.3022082f * u));
}

// radix-4 DIF, natural in -> base4-digit-reversed out, in-place on padded SoA LDS
__device__ __forceinline__ void fft4096_fwd(float* re, float* im, const float2* tw, int t) {
    for (int s = 5; s >= 0; --s) {
        int m = 1 << (2*s);
        int rsh = 10 - 2*s;
        #pragma unroll
        for (int it = 0; it < 4; ++it) {
            int j = t + 256*it;
            int p = j & (m-1);
            int g = j >> (2*s);
            int i0 = (g << (2*s+2)) + p;
            int i1 = i0 + m, i2 = i0 + 2*m, i3 = i0 + 3*m;
            float ar = re[PD(i0)], ai = im[PD(i0)];
            float br = re[PD(i1)], bi = im[PD(i1)];
            float cr = re[PD(i2)], ci = im[PD(i2)];
            float dr = re[PD(i3)], di = im[PD(i3)];
            float t0r = ar+cr, t0i = ai+ci;
            float t1r = ar-cr, t1i = ai-ci;
            float t2r = br+dr, t2i = bi+di;
            float t3r = br-dr, t3i = bi-di;
            float A0r = t0r+t2r, A0i = t0i+t2i;
            float A2r = t0r-t2r, A2i = t0i-t2i;
            float A1r = t1r+t3i, A1i = t1i-t3r;   // t1 - i*t3
            float A3r = t1r-t3i, A3i = t1i+t3r;   // t1 + i*t3
            int e1 = p << rsh;
            int e2 = e1 << 1;
            int e3 = e2 + e1;
            float2 w1 = tw[e1];
            float2 w2 = tw[e2];
            float2 w3 = (e3 < N2/2) ? tw[e3] : tw[e3 - N2/2];
            float s3 = (e3 < N2/2) ? 1.0f : -1.0f;
            re[PD(i0)] = A0r;                       im[PD(i0)] = A0i;
            re[PD(i1)] = A1r*w1.x - A1i*w1.y;       im[PD(i1)] = A1r*w1.y + A1i*w1.x;
            re[PD(i2)] = A2r*w2.x - A2i*w2.y;       im[PD(i2)] = A2r*w2.y + A2i*w2.x;
            re[PD(i3)] = s3*(A3r*w3.x - A3i*w3.y);  im[PD(i3)] = s3*(A3r*w3.y + A3i*w3.x);
        }
        __syncthreads();
    }
}

// radix-4 DIT, base4-digit-reversed in -> natural out, conj twiddles (no 1/N scale)
__device__ __forceinline__ void fft4096_inv(float* re, float* im, const float2* tw, int t) {
    for (int s = 0; s <= 5; ++s) {
        int m = 1 << (2*s);
        int rsh = 10 - 2*s;
        #pragma unroll
        for (int it = 0; it < 4; ++it) {
            int j = t + 256*it;
            int p = j & (m-1);
            int g = j >> (2*s);
            int i0 = (g << (2*s+2)) + p;
            int i1 = i0 + m, i2 = i0 + 2*m, i3 = i0 + 3*m;
            float ar  = re[PD(i0)], ai  = im[PD(i0)];
            float br0 = re[PD(i1)], bi0 = im[PD(i1)];
            float cr0 = re[PD(i2)], ci0 = im[PD(i2)];
            float dr0 = re[PD(i3)], di0 = im[PD(i3)];
            int e1 = p << rsh;
            int e2 = e1 << 1;
            int e3 = e2 + e1;
            float2 w1 = tw[e1];
            float2 w2 = tw[e2];
            float2 w3 = (e3 < N2/2) ? tw[e3] : tw[e3 - N2/2];
            float s3 = (e3 < N2/2) ? 1.0f : -1.0f;
            // multiply by conj(w): (x,y)*conj(c,s) = (x*c + y*s, y*c - x*s)
            float br = br0*w1.x + bi0*w1.y,        bi = bi0*w1.x - br0*w1.y;
            float cr = cr0*w2.x + ci0*w2.y,        ci = ci0*w2.x - cr0*w2.y;
            float drr = s3*(dr0*w3.x + di0*w3.y),  dii = s3*(di0*w3.x - dr0*w3.y);
            float t0r = ar+cr, t0i = ai+ci;
            float t1r = ar-cr, t1i = ai-ci;
            float t2r = br+drr, t2i = bi+dii;
            float t3r = br-drr, t3i = bi-dii;
            re[PD(i0)] = t0r+t2r;  im[PD(i0)] = t0i+t2i;
            re[PD(i2)] = t0r-t2r;  im[PD(i2)] = t0i-t2i;
            re[PD(i1)] = t1r-t3i;  im[PD(i1)] = t1i+t3r;   // t1 + i*t3
            re[PD(i3)] = t1r+t3i;  im[PD(i3)] = t1i-t3r;   // t1 - i*t3
        }
        __syncthreads();
    }
}

// ---------------- kernel 0: count zeros per batch ----------------
__global__ void count_kernel(const float* __restrict__ mask, int* __restrict__ cz) {
    int b = blockIdx.x;
    int t = threadIdx.x;
    float s = 0.0f;
    for (int j = t; j < S_; j += 256) s += 1.0f - mask[b*S_ + j];
    for (int off = 32; off; off >>= 1) s += __shfl_xor(s, off);
    __shared__ float red[4];
    if ((t & 63) == 0) red[t >> 6] = s;
    __syncthreads();
    if (t == 0) {
        float tot = red[0] + red[1] + red[2] + red[3];
        cz[b] = (int)(tot + 0.5f);
    }
}

// ---------------- kernel 1: W_glu (K,N) f32 -> Wt (N,K) bf16 ----------------
__global__ void wprep_kernel(const float* __restrict__ W, unsigned short* __restrict__ Wt) {
    int idx = blockIdx.x * 256 + threadIdx.x;   // idx = n*512 + k
    int n = idx >> 9, k = idx & 511;
    Wt[idx] = f2bf(W[k*H_ + n]);
}

// ---------------- kernel 2: per-channel kernel spectrum (dr4-ordered), 1/N folded ----------------
__global__ __launch_bounds__(256) void kfft_kernel(
        const float* __restrict__ log_dt, const float* __restrict__ log_A_real,
        const float* __restrict__ A_imag,
        const float* __restrict__ B_re, const float* __restrict__ B_im,
        const float* __restrict__ C_re, const float* __restrict__ C_im,
        float2* __restrict__ Kf2) {   // laid out [hpair][N2][2]
    int h = blockIdx.x, t = threadIdx.x;
    __shared__ float re[N2 + N2/32];
    __shared__ float im[N2 + N2/32];
    __shared__ float2 tw[N2/2];
    __shared__ float lnr[NS_], ctr[NS_], cti[NS_];
    __shared__ double th[NS_];

    float dt = expf(log_dt[h]);
    if (t < NS_) {
        int n = t;
        float Ar = -expf(log_A_real[h*NS_ + n]);
        float Ai = A_imag[h*NS_ + n];
        float drr = 1.0f - 0.5f*dt*Ar, dii = -0.5f*dt*Ai;   // 1 - dtA/2
        float nr = 1.0f + 0.5f*dt*Ar, ni =  0.5f*dt*Ai;     // 1 + dtA/2
        float den = drr*drr + dii*dii;
        float dAr = (nr*drr + ni*dii) / den;
        float dAi = (ni*drr - nr*dii) / den;
        float cr = C_re[h*NS_+n], ci = C_im[h*NS_+n];
        float br = B_re[h*NS_+n], bi = B_im[h*NS_+n];
        float pr = (cr*br - ci*bi) * dt, pi = (cr*bi + ci*br) * dt;
        float qr = (pr*drr + pi*dii) / den;
        float qi = (pi*drr - pr*dii) / den;
        lnr[n] = 0.5f * logf(dAr*dAr + dAi*dAi);
        th[n]  = atan2((double)dAi, (double)dAr);
        ctr[n] = qr; cti[n] = qi;
    }
    for (int j = t; j < N2/2; j += 256) {
        float a = (float)((double)j * (-6.283185307179586 / (double)N2));
        float sv, cv; __sincosf(a, &sv, &cv);
        // use precise sincos for twiddles
        sincosf(a, &sv, &cv);
        tw[j] = make_float2(cv, sv);
    }
    __syncthreads();

    const double TWO_PI = 6.283185307179586;
    for (int l = t; l < S_; l += 256) {
        float acc = 0.0f;
        for (int n = 0; n < NS_; ++n) {
            float mag = expf((float)l * lnr[n]);
            double ad = (double)l * th[n];
            ad -= floor(ad / TWO_PI + 0.5) * TWO_PI;
            float a = (float)ad;
            float sv, cv; sincosf(a, &sv, &cv);
            acc += ctr[n]*(mag*cv) - cti[n]*(mag*sv);
        }
        re[PD(l)] = 2.0f*acc; im[PD(l)] = 0.0f;
    }
    for (int j = t + S_; j < N2; j += 256) { re[PD(j)] = 0.0f; im[PD(j)] = 0.0f; }
    __syncthreads();

    fft4096_fwd(re, im, tw, t);

    const float scale = 1.0f / (float)N2;   // fold irfft 1/N here
    int hp = h >> 1, sl = h & 1;
    for (int j = t; j < N2; j += 256) {
        Kf2[((size_t)hp*N2 + j)*2 + sl] = make_float2(re[PD(j)]*scale, im[PD(j)]*scale);
    }
}

// ---------------- kernel 3: LayerNorm + build z_t (B,H,S) with reversed half ----------------
__global__ __launch_bounds__(256) void ln_kernel(
        const float* __restrict__ x, const float* __restrict__ gamma,
        const float* __restrict__ beta, const int* __restrict__ cz,
        float* __restrict__ z_t) {
    int blk = blockIdx.x;
    int b = blk >> 6;            // 64 s-tiles of 32 per batch
    int s0 = (blk & 63) * 32;
    int t = threadIdx.x;
    int lane = t & 63, wave = t >> 6;
    __shared__ float st[32][257];

    float4 g4  = *(const float4*)(gamma + lane*4);
    float4 be4 = *(const float4*)(beta  + lane*4);
    for (int q = 0; q < 8; ++q) {
        int row = wave*8 + q;
        int s = s0 + row;
        float4 v = *(const float4*)(x + ((size_t)(b*S_ + s))*D_ + lane*4);
        float sum = v.x + v.y + v.z + v.w;
        float ss  = v.x*v.x + v.y*v.y + v.z*v.z + v.w*v.w;
        for (int off = 32; off; off >>= 1) {
            sum += __shfl_xor(sum, off);
            ss  += __shfl_xor(ss, off);
        }
        float mean = sum * (1.0f/(float)D_);
        float var  = ss  * (1.0f/(float)D_) - mean*mean;
        float rstd = rsqrtf(var + 1e-5f);
        st[row][lane*4+0] = (v.x - mean)*rstd*g4.x + be4.x;
        st[row][lane*4+1] = (v.y - mean)*rstd*g4.y + be4.y;
        st[row][lane*4+2] = (v.z - mean)*rstd*g4.z + be4.z;
        st[row][lane*4+3] = (v.w - mean)*rstd*g4.w + be4.w;
    }
    __syncthreads();
    int czb = cz[b];
    int s_off = t & 31, dg = t >> 5;
    int s = s0 + s_off;
    int bs = (2*S_ - 1 - czb - s) % S_;
    for (int i = 0; i < 32; ++i) {
        int d = dg + 8*i;
        float v = st[s_off][d];
        z_t[((size_t)(b*H_ + d      ))*S_ + s ] = v;   // forward channel d
        z_t[((size_t)(b*H_ + D_ + d ))*S_ + bs] = v;   // reversed channel D+d
    }
}

// ---------------- kernel 4: 2-channel packed FFT conv + D_skip + gelu, in place ----------------
__global__ __launch_bounds__(256) void fftconv_kernel(
        float* __restrict__ z_t, const float4* __restrict__ Kf4,
        const float* __restrict__ D_skip) {
    int blk = blockIdx.x;
    int b  = blk >> 8;           // H/2 = 256 pairs
    int hp = blk & 255;
    int h0 = hp * 2;
    int t = threadIdx.x;
    __shared__ float re[N2 + N2/32];
    __shared__ float im[N2 + N2/32];
    __shared__ float2 tw[N2/2];

    float* zrow1 = z_t + ((size_t)(b*H_ + h0    ))*S_;
    float* zrow2 = z_t + ((size_t)(b*H_ + h0 + 1))*S_;

    float z1r[8], z2r[8];
    #pragma unroll
    for (int it = 0; it < 8; ++it) {
        int s = t + 256*it;
        float v1 = zrow1[s], v2 = zrow2[s];
        z1r[it] = v1; z2r[it] = v2;
        re[PD(s)] = v1; im[PD(s)] = v2;
    }
    for (int j = t + S_; j < N2; j += 256) { re[PD(j)] = 0.0f; im[PD(j)] = 0.0f; }
    for (int j = t; j < N2/2; j += 256) {
        float a = (float)((double)j * (-6.283185307179586 / (double)N2));
        float sv, cv; sincosf(a, &sv, &cv);
        tw[j] = make_float2(cv, sv);
    }
    __syncthreads();

    fft4096_fwd(re, im, tw, t);

    // Hermitian split (2 real channels) + pointwise kernel multiply + repack
    float Wr[16], Wi[16];
    const float4* kp = Kf4 + (size_t)hp * N2;
    #pragma unroll
    for (int it = 0; it < 16; ++it) {
        int j = t + 256*it;
        int k = dr4(j);
        int kc = (N2 - k) & (N2 - 1);
        int j2 = dr4(kc);
        float za = re[PD(j)],  zb = im[PD(j)];
        float zc = re[PD(j2)], zd = im[PD(j2)];
        float Xr = 0.5f*(za + zc), Xi = 0.5f*(zb - zd);
        float Yr = 0.5f*(zb + zd), Yi = 0.5f*(zc - za);
        float4 kk = kp[j];
        float Pr = Xr*kk.x - Xi*kk.y, Pi = Xr*kk.y + Xi*kk.x;
        float Qr = Yr*kk.z - Yi*kk.w, Qi = Yr*kk.w + Yi*kk.z;
        Wr[it] = Pr - Qi; Wi[it] = Pi + Qr;
    }
    __syncthreads();
    #pragma unroll
    for (int it = 0; it < 16; ++it) {
        int j = t + 256*it;
        re[PD(j)] = Wr[it]; im[PD(j)] = Wi[it];
    }
    __syncthreads();

    fft4096_inv(re, im, tw, t);

    float dsk1 = D_skip[h0], dsk2 = D_skip[h0+1];
    #pragma unroll
    for (int it = 0; it < 8; ++it) {
        int s = t + 256*it;
        float y1 = re[PD(s)] + dsk1 * z1r[it];
        float y2 = im[PD(s)] + dsk2 * z2r[it];
        zrow1[s] = gelu_f(y1);
        zrow2[s] = gelu_f(y2);
    }
}

// ---------------- kernel 5: (B,H,S) f32 -> (B,S,H) bf16 with back-half re-reversal ----------------
__global__ __launch_bounds__(256) void transpose_kernel(
        const float* __restrict__ y_t, const int* __restrict__ cz,
        unsigned short* __restrict__ A) {
    int b  = blockIdx.z;
    int h0 = blockIdx.y * 64;
    int s0 = blockIdx.x * 64;
    int t = threadIdx.x;
    int tx = t & 63, ty = t >> 6;
    __shared__ float tile[64][65];
    bool back = (h0 >= D_);
    int czb = cz[b];
    int s = s0 + tx;
    int scol = back ? ((2*S_ - 1 - czb - s) % S_) : s;
    for (int i = 0; i < 16; ++i) {
        int hh = ty*16 + i;
        tile[hh][tx] = y_t[((size_t)(b*H_ + h0 + hh))*S_ + scol];
    }
    __syncthreads();
    for (int i = 0; i < 16; ++i) {
        int sl = ty*16 + i;
        A[((size_t)(b*S_ + s0 + sl))*H_ + h0 + tx] = f2bf(tile[tx][sl]);
    }
}

// ---------------- kernel 6: GLU GEMM (MFMA bf16) + bias + sigmoid gate + residual ----------------
__global__ __launch_bounds__(256) void glu_gemm_kernel(
        const unsigned short* __restrict__ A, const unsigned short* __restrict__ Wt,
        const float* __restrict__ bglu, const float* __restrict__ x,
        float* __restrict__ out) {
    int m0 = blockIdx.x * 64;
    int n0 = blockIdx.y * 64;
    int t = threadIdx.x;
    int lane = t & 63, w = t >> 6;
    int wm = w & 1, wgrp = w >> 1;
    __shared__ __align__(16) short As[64][40];
    __shared__ __align__(16) short Bs[2][64][40];
    __shared__ float gs[64][132];

    f32x4 acc[2][4];
    for (int mf = 0; mf < 2; ++mf)
        for (int nf = 0; nf < 4; ++nf)
            acc[mf][nf] = (f32x4){0.0f, 0.0f, 0.0f, 0.0f};

    int srow = t >> 2;
    int scol = (t & 3) * 8;
    for (int kk = 0; kk < H_; kk += 32) {
        __syncthreads();
        *(int4*)&As[srow][scol]    = *(const int4*)(A  + ((size_t)(m0 + srow))*H_ + kk + scol);
        *(int4*)&Bs[0][srow][scol] = *(const int4*)(Wt + ((size_t)(n0 + srow))*H_ + kk + scol);
        *(int4*)&Bs[1][srow][scol] = *(const int4*)(Wt + ((size_t)(n0 + 256 + srow))*H_ + kk + scol);
        __syncthreads();
        int lr = lane & 15, ks = (lane >> 4) * 8;
        bf16x8 af[2], bf[4];
        for (int mf = 0; mf < 2; ++mf)
            af[mf] = *(bf16x8*)&As[wm*32 + mf*16 + lr][ks];
        for (int nf = 0; nf < 4; ++nf)
            bf[nf] = *(bf16x8*)&Bs[wgrp][nf*16 + lr][ks];
        for (int mf = 0; mf < 2; ++mf)
            for (int nf = 0; nf < 4; ++nf)
                acc[mf][nf] = __builtin_amdgcn_mfma_f32_16x16x32_bf16(af[mf], bf[nf], acc[mf][nf], 0, 0, 0);
    }
    __syncthreads();
    for (int mf = 0; mf < 2; ++mf)
        for (int nf = 0; nf < 4; ++nf)
            for (int r = 0; r < 4; ++r) {
                int row = wm*32 + mf*16 + (lane >> 4)*4 + r;
                int col = wgrp*64 + nf*16 + (lane & 15);
                gs[row][col] = acc[mf][nf][r];
            }
    __syncthreads();
    int col = t & 63;
    float ba = bglu[n0 + col], bb = bglu[n0 + 256 + col];
    for (int i = 0; i < 16; ++i) {
        int row = (t >> 6)*16 + i;
        size_t mr = (size_t)(m0 + row);
        float av = gs[row][col]      + ba;
        float bv = gs[row][64 + col] + bb;
        float sig = 1.0f / (1.0f + expf(-bv));
        out[mr*D_ + n0 + col] = av*sig + x[mr*D_ + n0 + col];
    }
}

// ---------------- launch ----------------
extern "C" void kernel_launch(void* const* d_in, const int* in_sizes, int n_in,
                              void* d_out, int out_size, void* d_ws, size_t ws_size,
                              hipStream_t stream) {
    const float* x         = (const float*)d_in[0];
    const float* mask      = (const float*)d_in[1];
    const float* log_dt    = (const float*)d_in[2];
    const float* log_A_real= (const float*)d_in[3];
    const float* A_imag    = (const float*)d_in[4];
    const float* B_re      = (const float*)d_in[5];
    const float* B_im      = (const float*)d_in[6];
    const float* C_re      = (const float*)d_in[7];
    const float* C_im      = (const float*)d_in[8];
    const float* D_skip    = (const float*)d_in[9];
    const float* W_glu     = (const float*)d_in[10];
    const float* b_glu     = (const float*)d_in[11];
    const float* ln_gamma  = (const float*)d_in[12];
    const float* ln_beta   = (const float*)d_in[13];
    float* out = (float*)d_out;

    char* ws = (char*)d_ws;
    // layout: cz(256B) | z_t 64MB | Kf 16MB | A_bf16 32MB | Wt 0.5MB  => ~112.5 MB
    int*            cz  = (int*)ws;
    float*          z_t = (float*)(ws + 256);
    float2*         Kf2 = (float2*)(ws + 256 + 67108864);
    unsigned short* Abf = (unsigned short*)(ws + 256 + 67108864 + 16777216);
    unsigned short* Wt  = (unsigned short*)(ws + 256 + 67108864 + 16777216 + 33554432);

    count_kernel<<<B_, 256, 0, stream>>>(mask, cz);
    wprep_kernel<<<(H_*H_)/256, 256, 0, stream>>>(W_glu, Wt);
    kfft_kernel<<<H_, 256, 0, stream>>>(log_dt, log_A_real, A_imag, B_re, B_im, C_re, C_im, Kf2);
    ln_kernel<<<B_*(S_/32), 256, 0, stream>>>(x, ln_gamma, ln_beta, cz, z_t);
    fftconv_kernel<<<B_*(H_/2), 256, 0, stream>>>(z_t, (const float4*)Kf2, D_skip);
    transpose_kernel<<<dim3(S_/64, H_/64, B_), 256, 0, stream>>>(z_t, cz, Abf);
    glu_gemm_kernel<<<dim3(M_/64, D_/64), 256, 0, stream>>>(Abf, Wt, b_glu, x, out);
}

// Round 3
// 352.415 us; speedup vs baseline: 1.9292x; 1.5229x over previous
//
#include <hip/hip_runtime.h>
#include <hip/hip_bf16.h>
#include <math.h>

#define B_ 16
#define S_ 2048
#define D_ 256
#define H_ 512
#define NS_ 64
#define N2 4096
#define M_ (B_*S_)
#define XP(i) ((i) + ((i) >> 4))

typedef float f32x4 __attribute__((ext_vector_type(4)));
typedef short bf16x8 __attribute__((ext_vector_type(8)));

__device__ __forceinline__ unsigned short f2bf(float x) {
    __hip_bfloat16 h = __float2bfloat16(x);
    return *reinterpret_cast<unsigned short*>(&h);
}

__device__ __forceinline__ float gelu_f(float y) {
    float u = y + 0.044715f*y*y*y;
    return y / (1.0f + __builtin_exp2f(-2.3022082f * u));
}

// ---------------- 16-point DFT in registers (2 x radix-4), no scaling ----------------
// fwd: omega = e^{-2pi i/16}; inv: conj
template<bool INV>
__device__ __forceinline__ void dft16(float* xr, float* xi) {
    const float SGN = INV ? 1.0f : -1.0f;
    // forward twiddle table W16[kl][n0] = e^{-2pi i kl*n0/16}
    constexpr float W16R[4][4] = {
        {1.f, 1.f, 1.f, 1.f},
        {1.f,  0.92387953251128674f,  0.70710678118654757f,  0.38268343236508984f},
        {1.f,  0.70710678118654757f,  0.0f,                 -0.70710678118654746f},
        {1.f,  0.38268343236508984f, -0.70710678118654746f, -0.92387953251128674f}};
    constexpr float W16I[4][4] = {
        {0.f, 0.f, 0.f, 0.f},
        {0.f, -0.38268343236508978f, -0.70710678118654746f, -0.92387953251128674f},
        {0.f, -0.70710678118654746f, -1.0f,                 -0.70710678118654757f},
        {0.f, -0.92387953251128674f, -0.70710678118654757f,  0.38268343236508967f}};
    float tr[16], ti[16];
    #pragma unroll
    for (int n0 = 0; n0 < 4; ++n0) {
        float ar = xr[n0],    ai = xi[n0];
        float br = xr[n0+4],  bi = xi[n0+4];
        float cr = xr[n0+8],  ci = xi[n0+8];
        float dr = xr[n0+12], di = xi[n0+12];
        float sacr = ar+cr, saci = ai+ci;
        float dacr = ar-cr, daci = ai-ci;
        float sbdr = br+dr, sbdi = bi+di;
        float dbdr = br-dr, dbdi = bi-di;
        tr[0*4+n0] = sacr + sbdr;      ti[0*4+n0] = saci + sbdi;
        tr[2*4+n0] = sacr - sbdr;      ti[2*4+n0] = saci - sbdi;
        tr[1*4+n0] = dacr - SGN*dbdi;  ti[1*4+n0] = daci + SGN*dbdr;
        tr[3*4+n0] = dacr + SGN*dbdi;  ti[3*4+n0] = daci - SGN*dbdr;
    }
    #pragma unroll
    for (int kl = 1; kl < 4; ++kl) {
        #pragma unroll
        for (int n0 = 1; n0 < 4; ++n0) {
            float wr = W16R[kl][n0];
            float wi = INV ? -W16I[kl][n0] : W16I[kl][n0];
            float pr = tr[kl*4+n0], pi = ti[kl*4+n0];
            tr[kl*4+n0] = pr*wr - pi*wi;
            ti[kl*4+n0] = pr*wi + pi*wr;
        }
    }
    #pragma unroll
    for (int kl = 0; kl < 4; ++kl) {
        float ar = tr[kl*4+0], ai = ti[kl*4+0];
        float br = tr[kl*4+1], bi = ti[kl*4+1];
        float cr = tr[kl*4+2], ci = ti[kl*4+2];
        float dr = tr[kl*4+3], di = ti[kl*4+3];
        float sacr = ar+cr, saci = ai+ci;
        float dacr = ar-cr, daci = ai-ci;
        float sbdr = br+dr, sbdi = bi+di;
        float dbdr = br-dr, dbdi = bi-di;
        xr[kl+0]  = sacr + sbdr;      xi[kl+0]  = saci + sbdi;
        xr[kl+8]  = sacr - sbdr;      xi[kl+8]  = saci - sbdi;
        xr[kl+4]  = dacr - SGN*dbdi;  xi[kl+4]  = daci + SGN*dbdr;
        xr[kl+12] = dacr + SGN*dbdi;  xi[kl+12] = daci - SGN*dbdr;
    }
}

// apply w^k (k=1..15) to regs via recurrence from base (w1r,w1i)
__device__ __forceinline__ void twiddle_recur(float* xr, float* xi, float w1r, float w1i) {
    float wr = w1r, wi = w1i;
    #pragma unroll
    for (int k = 1; k < 16; ++k) {
        float pr = xr[k], pi = xi[k];
        xr[k] = pr*wr - pi*wi;
        xi[k] = pr*wi + pi*wr;
        float nr = wr*w1r - wi*w1i;
        wi = wr*w1i + wi*w1r;
        wr = nr;
    }
}

// forward 4096-pt FFT: regs hold x[n1*256 + t] (reg idx n1). Output: regs hold
// X[k1+16k2+256k3] at reg idx k3, thread t = 16*k1 + k2  (sigma-slot s = 256*k3 + t)
__device__ __forceinline__ void fft4096_fwd_reg(float* xr, float* xi, float* lre, float* lim, int t) {
    dft16<false>(xr, xi);
    float w1r, w1i, ang;
    ang = (float)t * (-1.5339807878856412e-3f);      // -2pi/4096
    sincosf(ang, &w1i, &w1r);
    twiddle_recur(xr, xi, w1r, w1i);                 // * w4096^{t*k1}
    #pragma unroll
    for (int k = 0; k < 16; ++k) { int idx = XP(k*256 + t); lre[idx] = xr[k]; lim[idx] = xi[k]; }
    __syncthreads();
    int k1 = t >> 4, n3 = t & 15;                    // role: t = k1*16 + n3
    #pragma unroll
    for (int n2 = 0; n2 < 16; ++n2) {
        int idx = XP(k1*256 + n2*16 + n3);
        xr[n2] = lre[idx]; xi[n2] = lim[idx];
    }
    dft16<false>(xr, xi);                            // over n2 -> k2
    ang = (float)n3 * (-2.4543692606170260e-2f);     // -2pi/256
    sincosf(ang, &w1i, &w1r);
    twiddle_recur(xr, xi, w1r, w1i);                 // * w256^{n3*k2}
    __syncthreads();
    #pragma unroll
    for (int k = 0; k < 16; ++k) { int idx = XP(k1*256 + k*16 + n3); lre[idx] = xr[k]; lim[idx] = xi[k]; }
    __syncthreads();
    int k2 = t & 15;                                 // role: t = k1*16 + k2
    #pragma unroll
    for (int n3b = 0; n3b < 16; ++n3b) {
        int idx = XP(k1*256 + k2*16 + n3b);
        xr[n3b] = lre[idx]; xi[n3b] = lim[idx];
    }
    dft16<false>(xr, xi);                            // over n3 -> k3
}

// inverse: regs hold W at sigma-slots 256*k3 + t (reg idx k3). Output: x[n1*256 + t] (reg idx n1).
// Unscaled (1/4096 folded into kernel spectrum).
__device__ __forceinline__ void fft4096_inv_reg(float* xr, float* xi, float* lre, float* lim, int t) {
    int k1 = t >> 4, k2 = t & 15;
    dft16<true>(xr, xi);                             // over k3 -> n3
    float w1r, w1i, ang;
    ang = (float)k2 * (2.4543692606170260e-2f);      // +2pi/256
    sincosf(ang, &w1i, &w1r);
    twiddle_recur(xr, xi, w1r, w1i);                 // * conj(w256)^{n3*k2}
    __syncthreads();                                 // prior LDS reads complete
    #pragma unroll
    for (int k = 0; k < 16; ++k) { int idx = XP(k1*256 + k2*16 + k); lre[idx] = xr[k]; lim[idx] = xi[k]; }
    __syncthreads();
    int n3 = t & 15;                                 // role: t = k1*16 + n3
    #pragma unroll
    for (int c = 0; c < 16; ++c) {
        int idx = XP(k1*256 + c*16 + n3);
        xr[c] = lre[idx]; xi[c] = lim[idx];
    }
    dft16<true>(xr, xi);                             // over k2 -> n2
    __syncthreads();
    #pragma unroll
    for (int k = 0; k < 16; ++k) { int idx = XP(k1*256 + k*16 + n3); lre[idx] = xr[k]; lim[idx] = xi[k]; }
    __syncthreads();
    #pragma unroll
    for (int k = 0; k < 16; ++k) {
        int idx = XP(k*256 + t);
        xr[k] = lre[idx]; xi[k] = lim[idx];
    }
    ang = (float)t * (1.5339807878856412e-3f);       // +2pi/4096
    sincosf(ang, &w1i, &w1r);
    twiddle_recur(xr, xi, w1r, w1i);                 // * conj(w4096)^{t*k1}
    dft16<true>(xr, xi);                             // over k1 -> n1
}

// ---------------- kernel 0: count zeros per batch ----------------
__global__ void count_kernel(const float* __restrict__ mask, int* __restrict__ cz) {
    int b = blockIdx.x;
    int t = threadIdx.x;
    float s = 0.0f;
    for (int j = t; j < S_; j += 256) s += 1.0f - mask[b*S_ + j];
    for (int off = 32; off; off >>= 1) s += __shfl_xor(s, off);
    __shared__ float red[4];
    if ((t & 63) == 0) red[t >> 6] = s;
    __syncthreads();
    if (t == 0) {
        float tot = red[0] + red[1] + red[2] + red[3];
        cz[b] = (int)(tot + 0.5f);
    }
}

// ---------------- kernel 1: W_glu (K,N) f32 -> Wt (N,K) bf16 ----------------
__global__ void wprep_kernel(const float* __restrict__ W, unsigned short* __restrict__ Wt) {
    int idx = blockIdx.x * 256 + threadIdx.x;   // idx = n*512 + k
    int n = idx >> 9, k = idx & 511;
    Wt[idx] = f2bf(W[k*H_ + n]);
}

// ---------------- kernel 2: kernel spectra, 2 channels packed, sigma order, 1/N folded ----------------
__global__ __launch_bounds__(256) void kfft_kernel(
        const float* __restrict__ log_dt, const float* __restrict__ log_A_real,
        const float* __restrict__ A_imag,
        const float* __restrict__ B_re, const float* __restrict__ B_im,
        const float* __restrict__ C_re, const float* __restrict__ C_im,
        float4* __restrict__ Kout) {
    int hp = blockIdx.x, t = threadIdx.x;
    int h0 = hp * 2;
    __shared__ float lre[N2 + N2/16];
    __shared__ float lim[N2 + N2/16];
    __shared__ float lnr[2][NS_], ctr[2][NS_], cti[2][NS_];
    __shared__ double th[2][NS_];

    if (t < 128) {
        int ch = t >> 6, n = t & 63, h = h0 + ch;
        float dt = expf(log_dt[h]);
        float Ar = -expf(log_A_real[h*NS_ + n]);
        float Ai = A_imag[h*NS_ + n];
        float drr = 1.0f - 0.5f*dt*Ar, dii = -0.5f*dt*Ai;   // 1 - dtA/2
        float nr = 1.0f + 0.5f*dt*Ar, ni =  0.5f*dt*Ai;     // 1 + dtA/2
        float den = drr*drr + dii*dii;
        float dAr = (nr*drr + ni*dii) / den;
        float dAi = (ni*drr - nr*dii) / den;
        float cr = C_re[h*NS_+n], ci = C_im[h*NS_+n];
        float br = B_re[h*NS_+n], bi = B_im[h*NS_+n];
        float pr = (cr*br - ci*bi) * dt, pi = (cr*bi + ci*br) * dt;
        float qr = (pr*drr + pi*dii) / den;
        float qi = (pi*drr - pr*dii) / den;
        lnr[ch][n] = 0.5f * logf(dAr*dAr + dAi*dAi);
        th[ch][n]  = atan2((double)dAi, (double)dAr);
        ctr[ch][n] = qr; cti[ch][n] = qi;
    }
    __syncthreads();

    float xr[16], xi[16];
    #pragma unroll
    for (int j = 0; j < 16; ++j) { xr[j] = 0.0f; xi[j] = 0.0f; }

    const double TWO_PI = 6.283185307179586;
    #pragma unroll
    for (int ch = 0; ch < 2; ++ch) {
        for (int n = 0; n < NS_; ++n) {
            float lr = lnr[ch][n];
            double thn = th[ch][n];
            double a0 = thn * (double)t;
            a0 -= floor(a0/TWO_PI + 0.5)*TWO_PI;
            float mb = expf(lr * (float)t);
            float sb, cb; sincosf((float)a0, &sb, &cb);
            float vr = mb*cb, vi = mb*sb;
            double as = thn * 256.0;
            as -= floor(as/TWO_PI + 0.5)*TWO_PI;
            float ms = expf(lr * 256.0f);
            float ss, cs; sincosf((float)as, &ss, &cs);
            float str = ms*cs, sti = ms*ss;
            float cr = ctr[ch][n], ci = cti[ch][n];
            #pragma unroll
            for (int j = 0; j < 8; ++j) {
                float contrib = cr*vr - ci*vi;
                if (ch == 0) xr[j] += contrib; else xi[j] += contrib;
                float nvr = vr*str - vi*sti;
                vi = vr*sti + vi*str;
                vr = nvr;
            }
        }
    }
    #pragma unroll
    for (int j = 0; j < 8; ++j) { xr[j] *= 2.0f; xi[j] *= 2.0f; }
    // regs: xr = K_{h0}[256*j + t], xi = K_{h1}[256*j + t], zero-padded j>=8

    fft4096_fwd_reg(xr, xi, lre, lim, t);

    __syncthreads();
    #pragma unroll
    for (int k = 0; k < 16; ++k) { int idx = XP(k*256 + t); lre[idx] = xr[k]; lim[idx] = xi[k]; }
    __syncthreads();

    const float scale = 1.0f / (float)N2;
    #pragma unroll
    for (int it = 0; it < 16; ++it) {
        int j = 256*it + t;
        int k = (t >> 4) + ((t & 15) << 4) + (it << 8);
        int kc = (N2 - k) & (N2 - 1);
        int j2 = ((kc >> 8) << 8) + ((kc & 15) << 4) + ((kc >> 4) & 15);
        float za = xr[it], zb = xi[it];
        float zc = lre[XP(j2)], zd = lim[XP(j2)];
        float Xr = 0.5f*(za + zc), Xi2 = 0.5f*(zb - zd);
        float Yr = 0.5f*(zb + zd), Yi = 0.5f*(zc - za);
        Kout[(size_t)hp*N2 + j] = make_float4(Xr*scale, Xi2*scale, Yr*scale, Yi*scale);
    }
}

// ---------------- kernel 3: LayerNorm + build z_t (B,H,S) with reversed half ----------------
__global__ __launch_bounds__(256) void ln_kernel(
        const float* __restrict__ x, const float* __restrict__ gamma,
        const float* __restrict__ beta, const int* __restrict__ cz,
        float* __restrict__ z_t) {
    int blk = blockIdx.x;
    int b = blk >> 6;
    int s0 = (blk & 63) * 32;
    int t = threadIdx.x;
    int lane = t & 63, wave = t >> 6;
    __shared__ float st[32][257];

    float4 g4  = *(const float4*)(gamma + lane*4);
    float4 be4 = *(const float4*)(beta  + lane*4);
    for (int q = 0; q < 8; ++q) {
        int row = wave*8 + q;
        int s = s0 + row;
        float4 v = *(const float4*)(x + ((size_t)(b*S_ + s))*D_ + lane*4);
        float sum = v.x + v.y + v.z + v.w;
        float ss  = v.x*v.x + v.y*v.y + v.z*v.z + v.w*v.w;
        for (int off = 32; off; off >>= 1) {
            sum += __shfl_xor(sum, off);
            ss  += __shfl_xor(ss, off);
        }
        float mean = sum * (1.0f/(float)D_);
        float var  = ss  * (1.0f/(float)D_) - mean*mean;
        float rstd = rsqrtf(var + 1e-5f);
        st[row][lane*4+0] = (v.x - mean)*rstd*g4.x + be4.x;
        st[row][lane*4+1] = (v.y - mean)*rstd*g4.y + be4.y;
        st[row][lane*4+2] = (v.z - mean)*rstd*g4.z + be4.z;
        st[row][lane*4+3] = (v.w - mean)*rstd*g4.w + be4.w;
    }
    __syncthreads();
    int czb = cz[b];
    int s_off = t & 31, dg = t >> 5;
    int s = s0 + s_off;
    int bs = (2*S_ - 1 - czb - s) % S_;
    for (int i = 0; i < 32; ++i) {
        int d = dg + 8*i;
        float v = st[s_off][d];
        z_t[((size_t)(b*H_ + d      ))*S_ + s ] = v;
        z_t[((size_t)(b*H_ + D_ + d ))*S_ + bs] = v;
    }
}

// ---------------- kernel 4: packed FFT conv + D_skip + gelu -> bf16 ----------------
__global__ __launch_bounds__(256) void fftconv_kernel(
        const float* __restrict__ z_t, const float4* __restrict__ Kf4,
        const float* __restrict__ D_skip, unsigned short* __restrict__ ybf) {
    int blk = blockIdx.x;
    int b  = blk >> 8;
    int hp = blk & 255;
    int h0 = hp * 2;
    int t = threadIdx.x;
    __shared__ float lre[N2 + N2/16];
    __shared__ float lim[N2 + N2/16];

    const float* zrow1 = z_t + ((size_t)(b*H_ + h0    ))*S_;
    const float* zrow2 = z_t + ((size_t)(b*H_ + h0 + 1))*S_;
    float xr[16], xi[16];
    float z1r[8], z2r[8];
    #pragma unroll
    for (int j = 0; j < 8; ++j) {
        int s = t + 256*j;
        float v1 = zrow1[s], v2 = zrow2[s];
        z1r[j] = v1; z2r[j] = v2;
        xr[j] = v1;  xi[j] = v2;
        xr[j+8] = 0.0f; xi[j+8] = 0.0f;
    }

    fft4096_fwd_reg(xr, xi, lre, lim, t);

    __syncthreads();
    #pragma unroll
    for (int k = 0; k < 16; ++k) { int idx = XP(k*256 + t); lre[idx] = xr[k]; lim[idx] = xi[k]; }
    __syncthreads();

    const float4* kp = Kf4 + (size_t)hp * N2;
    #pragma unroll
    for (int it = 0; it < 16; ++it) {
        int j = 256*it + t;
        int k = (t >> 4) + ((t & 15) << 4) + (it << 8);
        int kc = (N2 - k) & (N2 - 1);
        int j2 = ((kc >> 8) << 8) + ((kc & 15) << 4) + ((kc >> 4) & 15);
        float za = xr[it], zb = xi[it];
        float zc = lre[XP(j2)], zd = lim[XP(j2)];
        float Xr = 0.5f*(za + zc), Xi2 = 0.5f*(zb - zd);
        float Yr = 0.5f*(zb + zd), Yi = 0.5f*(zc - za);
        float4 kk = kp[j];
        float Pr = Xr*kk.x - Xi2*kk.y, Pi = Xr*kk.y + Xi2*kk.x;
        float Qr = Yr*kk.z - Yi*kk.w,  Qi = Yr*kk.w + Yi*kk.z;
        xr[it] = Pr - Qi;
        xi[it] = Pi + Qr;
    }

    fft4096_inv_reg(xr, xi, lre, lim, t);

    float dsk1 = D_skip[h0], dsk2 = D_skip[h0+1];
    unsigned short* yb1 = ybf + ((size_t)(b*H_ + h0    ))*2*S_;
    unsigned short* yb2 = ybf + ((size_t)(b*H_ + h0 + 1))*2*S_;
    #pragma unroll
    for (int j = 0; j < 8; ++j) {
        int s = t + 256*j;
        float y1 = xr[j] + dsk1 * z1r[j];
        float y2 = xi[j] + dsk2 * z2r[j];
        yb1[s] = f2bf(gelu_f(y1));
        yb2[s] = f2bf(gelu_f(y2));
    }
}

// ---------------- kernel 5: (B,H,2S)bf16 rows -> (B,S,H) bf16 with back-half re-reversal ----------------
__global__ __launch_bounds__(256) void transpose_kernel(
        const unsigned short* __restrict__ ybf, const int* __restrict__ cz,
        unsigned short* __restrict__ A) {
    int b  = blockIdx.z;
    int h0 = blockIdx.y * 64;
    int s0 = blockIdx.x * 64;
    int t = threadIdx.x;
    int tx = t & 63, ty = t >> 6;
    __shared__ unsigned short tile[64][65];
    bool back = (h0 >= D_);
    int czb = cz[b];
    int s = s0 + tx;
    int scol = back ? ((2*S_ - 1 - czb - s) % S_) : s;
    for (int i = 0; i < 16; ++i) {
        int hh = ty*16 + i;
        tile[hh][tx] = ybf[((size_t)(b*H_ + h0 + hh))*2*S_ + scol];
    }
    __syncthreads();
    for (int i = 0; i < 16; ++i) {
        int sl = ty*16 + i;
        A[((size_t)(b*S_ + s0 + sl))*H_ + h0 + tx] = tile[tx][sl];
    }
}

// ---------------- kernel 6: GLU GEMM (MFMA bf16) + bias + sigmoid gate + residual ----------------
__global__ __launch_bounds__(256) void glu_gemm_kernel(
        const unsigned short* __restrict__ A, const unsigned short* __restrict__ Wt,
        const float* __restrict__ bglu, const float* __restrict__ x,
        float* __restrict__ out) {
    int m0 = blockIdx.x * 64;
    int n0 = blockIdx.y * 64;
    int t = threadIdx.x;
    int lane = t & 63, w = t >> 6;
    int wm = w & 1, wgrp = w >> 1;
    __shared__ __align__(16) short As[64][40];
    __shared__ __align__(16) short Bs[2][64][40];
    __shared__ float gs[64][132];

    f32x4 acc[2][4];
    for (int mf = 0; mf < 2; ++mf)
        for (int nf = 0; nf < 4; ++nf)
            acc[mf][nf] = (f32x4){0.0f, 0.0f, 0.0f, 0.0f};

    int srow = t >> 2;
    int scol = (t & 3) * 8;
    for (int kk = 0; kk < H_; kk += 32) {
        __syncthreads();
        *(int4*)&As[srow][scol]    = *(const int4*)(A  + ((size_t)(m0 + srow))*H_ + kk + scol);
        *(int4*)&Bs[0][srow][scol] = *(const int4*)(Wt + ((size_t)(n0 + srow))*H_ + kk + scol);
        *(int4*)&Bs[1][srow][scol] = *(const int4*)(Wt + ((size_t)(n0 + 256 + srow))*H_ + kk + scol);
        __syncthreads();
        int lr = lane & 15, ks = (lane >> 4) * 8;
        bf16x8 af[2], bf[4];
        for (int mf = 0; mf < 2; ++mf)
            af[mf] = *(bf16x8*)&As[wm*32 + mf*16 + lr][ks];
        for (int nf = 0; nf < 4; ++nf)
            bf[nf] = *(bf16x8*)&Bs[wgrp][nf*16 + lr][ks];
        for (int mf = 0; mf < 2; ++mf)
            for (int nf = 0; nf < 4; ++nf)
                acc[mf][nf] = __builtin_amdgcn_mfma_f32_16x16x32_bf16(af[mf], bf[nf], acc[mf][nf], 0, 0, 0);
    }
    __syncthreads();
    for (int mf = 0; mf < 2; ++mf)
        for (int nf = 0; nf < 4; ++nf)
            for (int r = 0; r < 4; ++r) {
                int row = wm*32 + mf*16 + (lane >> 4)*4 + r;
                int col = wgrp*64 + nf*16 + (lane & 15);
                gs[row][col] = acc[mf][nf][r];
            }
    __syncthreads();
    int col = t & 63;
    float ba = bglu[n0 + col], bb = bglu[n0 + 256 + col];
    for (int i = 0; i < 16; ++i) {
        int row = (t >> 6)*16 + i;
        size_t mr = (size_t)(m0 + row);
        float av = gs[row][col]      + ba;
        float bv = gs[row][64 + col] + bb;
        float sig = 1.0f / (1.0f + expf(-bv));
        out[mr*D_ + n0 + col] = av*sig + x[mr*D_ + n0 + col];
    }
}

// ---------------- launch ----------------
extern "C" void kernel_launch(void* const* d_in, const int* in_sizes, int n_in,
                              void* d_out, int out_size, void* d_ws, size_t ws_size,
                              hipStream_t stream) {
    const float* x         = (const float*)d_in[0];
    const float* mask      = (const float*)d_in[1];
    const float* log_dt    = (const float*)d_in[2];
    const float* log_A_real= (const float*)d_in[3];
    const float* A_imag    = (const float*)d_in[4];
    const float* B_re      = (const float*)d_in[5];
    const float* B_im      = (const float*)d_in[6];
    const float* C_re      = (const float*)d_in[7];
    const float* C_im      = (const float*)d_in[8];
    const float* D_skip    = (const float*)d_in[9];
    const float* W_glu     = (const float*)d_in[10];
    const float* b_glu     = (const float*)d_in[11];
    const float* ln_gamma  = (const float*)d_in[12];
    const float* ln_beta   = (const float*)d_in[13];
    float* out = (float*)d_out;

    char* ws = (char*)d_ws;
    // layout: cz(256B) | z_t 64MB (bf16 output aliased in-place) | Kf 16MB | A_bf16 32MB | Wt 0.5MB
    int*            cz  = (int*)ws;
    float*          z_t = (float*)(ws + 256);
    float4*         Kf  = (float4*)(ws + 256 + 67108864);
    unsigned short* Abf = (unsigned short*)(ws + 256 + 67108864 + 16777216);
    unsigned short* Wt  = (unsigned short*)(ws + 256 + 67108864 + 16777216 + 33554432);
    unsigned short* ybf = (unsigned short*)z_t;   // in-place: each block writes bf16 into its own rows' bytes

    count_kernel<<<B_, 256, 0, stream>>>(mask, cz);
    wprep_kernel<<<(H_*H_)/256, 256, 0, stream>>>(W_glu, Wt);
    kfft_kernel<<<H_/2, 256, 0, stream>>>(log_dt, log_A_real, A_imag, B_re, B_im, C_re, C_im, Kf);
    ln_kernel<<<B_*(S_/32), 256, 0, stream>>>(x, ln_gamma, ln_beta, cz, z_t);
    fftconv_kernel<<<B_*(H_/2), 256, 0, stream>>>(z_t, (const float4*)Kf, D_skip, ybf);
    transpose_kernel<<<dim3(S_/64, H_/64, B_), 256, 0, stream>>>(ybf, cz, Abf);
    glu_gemm_kernel<<<dim3(M_/64, D_/64), 256, 0, stream>>>(Abf, Wt, b_glu, x, out);
}

// Round 4
// 299.772 us; speedup vs baseline: 2.2680x; 1.1756x over previous
//
#include <hip/hip_runtime.h>
#include <hip/hip_bf16.h>
#include <math.h>

#define B_ 16
#define S_ 2048
#define D_ 256
#define H_ 512
#define NS_ 64
#define N2 4096
#define M_ (B_*S_)
#define XP(i) ((i) + ((i) >> 4))

typedef float f32x4 __attribute__((ext_vector_type(4)));
typedef short bf16x8 __attribute__((ext_vector_type(8)));

__device__ __forceinline__ unsigned short f2bf(float x) {
    __hip_bfloat16 h = __float2bfloat16(x);
    return *reinterpret_cast<unsigned short*>(&h);
}

__device__ __forceinline__ float gelu_f(float y) {
    float u = y + 0.044715f*y*y*y;
    return y / (1.0f + __builtin_exp2f(-2.3022082f * u));
}

// hw trig on revolutions (input must be range-reduced; ours are in [0,1))
__device__ __forceinline__ float cos_rev(float r) { return __builtin_amdgcn_cosf(r); }
__device__ __forceinline__ float sin_rev(float r) { return __builtin_amdgcn_sinf(r); }

// ---------------- 16-point DFT in registers (2 x radix-4) ----------------
// MODE 0: full.  MODE 1: inputs 8..15 are zero.  MODE 2: only outputs 0..7 needed.
template<bool INV, int MODE>
__device__ __forceinline__ void dft16(float* xr, float* xi) {
    const float SGN = INV ? 1.0f : -1.0f;
    constexpr float W16R[4][4] = {
        {1.f, 1.f, 1.f, 1.f},
        {1.f,  0.92387953251128674f,  0.70710678118654757f,  0.38268343236508984f},
        {1.f,  0.70710678118654757f,  0.0f,                 -0.70710678118654746f},
        {1.f,  0.38268343236508984f, -0.70710678118654746f, -0.92387953251128674f}};
    constexpr float W16I[4][4] = {
        {0.f, 0.f, 0.f, 0.f},
        {0.f, -0.38268343236508978f, -0.70710678118654746f, -0.92387953251128674f},
        {0.f, -0.70710678118654746f, -1.0f,                 -0.70710678118654757f},
        {0.f, -0.92387953251128674f, -0.70710678118654757f,  0.38268343236508967f}};
    float tr[16], ti[16];
    #pragma unroll
    for (int n0 = 0; n0 < 4; ++n0) {
        if (MODE == 1) {
            float ar = xr[n0],   ai = xi[n0];
            float br = xr[n0+4], bi = xi[n0+4];
            tr[0*4+n0] = ar + br;        ti[0*4+n0] = ai + bi;
            tr[2*4+n0] = ar - br;        ti[2*4+n0] = ai - bi;
            tr[1*4+n0] = ar - SGN*bi;    ti[1*4+n0] = ai + SGN*br;
            tr[3*4+n0] = ar + SGN*bi;    ti[3*4+n0] = ai - SGN*br;
        } else {
            float ar = xr[n0],    ai = xi[n0];
            float br = xr[n0+4],  bi = xi[n0+4];
            float cr = xr[n0+8],  ci = xi[n0+8];
            float dr = xr[n0+12], di = xi[n0+12];
            float sacr = ar+cr, saci = ai+ci;
            float dacr = ar-cr, daci = ai-ci;
            float sbdr = br+dr, sbdi = bi+di;
            float dbdr = br-dr, dbdi = bi-di;
            tr[0*4+n0] = sacr + sbdr;      ti[0*4+n0] = saci + sbdi;
            tr[2*4+n0] = sacr - sbdr;      ti[2*4+n0] = saci - sbdi;
            tr[1*4+n0] = dacr - SGN*dbdi;  ti[1*4+n0] = daci + SGN*dbdr;
            tr[3*4+n0] = dacr + SGN*dbdi;  ti[3*4+n0] = daci - SGN*dbdr;
        }
    }
    #pragma unroll
    for (int kl = 1; kl < 4; ++kl) {
        #pragma unroll
        for (int n0 = 1; n0 < 4; ++n0) {
            float wr = W16R[kl][n0];
            float wi = INV ? -W16I[kl][n0] : W16I[kl][n0];
            float pr = tr[kl*4+n0], pi = ti[kl*4+n0];
            tr[kl*4+n0] = pr*wr - pi*wi;
            ti[kl*4+n0] = pr*wi + pi*wr;
        }
    }
    #pragma unroll
    for (int kl = 0; kl < 4; ++kl) {
        float ar = tr[kl*4+0], ai = ti[kl*4+0];
        float br = tr[kl*4+1], bi = ti[kl*4+1];
        float cr = tr[kl*4+2], ci = ti[kl*4+2];
        float dr = tr[kl*4+3], di = ti[kl*4+3];
        float sacr = ar+cr, saci = ai+ci;
        float dacr = ar-cr, daci = ai-ci;
        float sbdr = br+dr, sbdi = bi+di;
        float dbdr = br-dr, dbdi = bi-di;
        xr[kl+0]  = sacr + sbdr;      xi[kl+0]  = saci + sbdi;
        xr[kl+4]  = dacr - SGN*dbdi;  xi[kl+4]  = daci + SGN*dbdr;
        if (MODE != 2) {
            xr[kl+8]  = sacr - sbdr;      xi[kl+8]  = saci - sbdi;
            xr[kl+12] = dacr + SGN*dbdi;  xi[kl+12] = daci - SGN*dbdr;
        }
    }
}

__device__ __forceinline__ void twiddle_recur(float* xr, float* xi, float w1r, float w1i) {
    float wr = w1r, wi = w1i;
    #pragma unroll
    for (int k = 1; k < 16; ++k) {
        float pr = xr[k], pi = xi[k];
        xr[k] = pr*wr - pi*wi;
        xi[k] = pr*wi + pi*wr;
        float nr = wr*w1r - wi*w1i;
        wi = wr*w1i + wi*w1r;
        wr = nr;
    }
}

// forward 4096-pt FFT (input zero-padded above 2048): regs in = x[n1*256+t] (reg n1),
// out = X[k1+16k2+256k3] at reg k3, thread t = 16*k1+k2 (sigma-slot s = 256*k3+t)
__device__ __forceinline__ void fft4096_fwd_reg(float* xr, float* xi, float* lre, float* lim, int t) {
    dft16<false, 1>(xr, xi);
    float rv = (float)t * (1.0f/4096.0f);
    float w1r = cos_rev(rv), w1i = -sin_rev(rv);
    twiddle_recur(xr, xi, w1r, w1i);
    #pragma unroll
    for (int k = 0; k < 16; ++k) { int idx = XP(k*256 + t); lre[idx] = xr[k]; lim[idx] = xi[k]; }
    __syncthreads();
    int k1 = t >> 4, n3 = t & 15;
    #pragma unroll
    for (int n2 = 0; n2 < 16; ++n2) {
        int idx = XP(k1*256 + n2*16 + n3);
        xr[n2] = lre[idx]; xi[n2] = lim[idx];
    }
    dft16<false, 0>(xr, xi);
    rv = (float)n3 * (1.0f/256.0f);
    w1r = cos_rev(rv); w1i = -sin_rev(rv);
    twiddle_recur(xr, xi, w1r, w1i);
    __syncthreads();
    #pragma unroll
    for (int k = 0; k < 16; ++k) { int idx = XP(k1*256 + k*16 + n3); lre[idx] = xr[k]; lim[idx] = xi[k]; }
    __syncthreads();
    int k2 = t & 15;
    #pragma unroll
    for (int n3b = 0; n3b < 16; ++n3b) {
        int idx = XP(k1*256 + k2*16 + n3b);
        xr[n3b] = lre[idx]; xi[n3b] = lim[idx];
    }
    dft16<false, 0>(xr, xi);
}

// inverse (unscaled): regs in = W at sigma-slots 256*k3+t (reg k3); out regs n1 (only 0..7 valid)
__device__ __forceinline__ void fft4096_inv_reg(float* xr, float* xi, float* lre, float* lim, int t) {
    int k1 = t >> 4, k2 = t & 15;
    dft16<true, 0>(xr, xi);
    float rv = (float)k2 * (1.0f/256.0f);
    float w1r = cos_rev(rv), w1i = sin_rev(rv);
    twiddle_recur(xr, xi, w1r, w1i);
    __syncthreads();
    #pragma unroll
    for (int k = 0; k < 16; ++k) { int idx = XP(k1*256 + k2*16 + k); lre[idx] = xr[k]; lim[idx] = xi[k]; }
    __syncthreads();
    int n3 = t & 15;
    #pragma unroll
    for (int c = 0; c < 16; ++c) {
        int idx = XP(k1*256 + c*16 + n3);
        xr[c] = lre[idx]; xi[c] = lim[idx];
    }
    dft16<true, 0>(xr, xi);
    __syncthreads();
    #pragma unroll
    for (int k = 0; k < 16; ++k) { int idx = XP(k1*256 + k*16 + n3); lre[idx] = xr[k]; lim[idx] = xi[k]; }
    __syncthreads();
    #pragma unroll
    for (int k = 0; k < 16; ++k) {
        int idx = XP(k*256 + t);
        xr[k] = lre[idx]; xi[k] = lim[idx];
    }
    rv = (float)t * (1.0f/4096.0f);
    w1r = cos_rev(rv); w1i = sin_rev(rv);
    twiddle_recur(xr, xi, w1r, w1i);
    dft16<true, 2>(xr, xi);
}

// ---------------- kernel 0: count zeros per batch ----------------
__global__ void count_kernel(const float* __restrict__ mask, int* __restrict__ cz) {
    int b = blockIdx.x;
    int t = threadIdx.x;
    float s = 0.0f;
    for (int j = t; j < S_; j += 256) s += 1.0f - mask[b*S_ + j];
    for (int off = 32; off; off >>= 1) s += __shfl_xor(s, off);
    __shared__ float red[4];
    if ((t & 63) == 0) red[t >> 6] = s;
    __syncthreads();
    if (t == 0) {
        float tot = red[0] + red[1] + red[2] + red[3];
        cz[b] = (int)(tot + 0.5f);
    }
}

// ---------------- kernel 1: W_glu (K,N) f32 -> Wt (N,K) bf16 ----------------
__global__ void wprep_kernel(const float* __restrict__ W, unsigned short* __restrict__ Wt) {
    int idx = blockIdx.x * 256 + threadIdx.x;
    int n = idx >> 9, k = idx & 511;
    Wt[idx] = f2bf(W[k*H_ + n]);
}

// ---------------- kernel 2: kernel spectra (2ch packed, sigma order, 1/N folded) ----------------
__global__ __launch_bounds__(256) void kfft_kernel(
        const float* __restrict__ log_dt, const float* __restrict__ log_A_real,
        const float* __restrict__ A_imag,
        const float* __restrict__ B_re, const float* __restrict__ B_im,
        const float* __restrict__ C_re, const float* __restrict__ C_im,
        float4* __restrict__ Kout) {
    int hp = blockIdx.x, t = threadIdx.x;
    int h0 = hp * 2;
    __shared__ float lre[N2 + N2/16];
    __shared__ float lim[N2 + N2/16];
    __shared__ float thrv[2][NS_], lnr2[2][NS_], ctr[2][NS_], cti[2][NS_];
    __shared__ float stpr[2][NS_], stpi[2][NS_];

    if (t < 128) {
        int ch = t >> 6, n = t & 63, h = h0 + ch;
        float dt = expf(log_dt[h]);
        float Ar = -expf(log_A_real[h*NS_ + n]);
        float Ai = A_imag[h*NS_ + n];
        float drr = 1.0f - 0.5f*dt*Ar, dii = -0.5f*dt*Ai;
        float nr = 1.0f + 0.5f*dt*Ar, ni =  0.5f*dt*Ai;
        float den = drr*drr + dii*dii;
        float dAr = (nr*drr + ni*dii) / den;
        float dAi = (ni*drr - nr*dii) / den;
        float cr = C_re[h*NS_+n], ci = C_im[h*NS_+n];
        float br = B_re[h*NS_+n], bi = B_im[h*NS_+n];
        float pr = (cr*br - ci*bi) * dt, pi = (cr*bi + ci*br) * dt;
        float qr = (pr*drr + pi*dii) / den;
        float qi = (pi*drr - pr*dii) / den;
        float trv = atan2f(dAi, dAr) * 0.15915494309189535f;   // theta / 2pi
        float l2  = 0.5f * log2f(dAr*dAr + dAi*dAi);           // log2|dA|
        thrv[ch][n] = trv; lnr2[ch][n] = l2;
        ctr[ch][n] = qr;   cti[ch][n] = qi;
        float ms = __builtin_exp2f(l2 * 256.0f);
        float rv = trv * 256.0f; rv -= floorf(rv);
        stpr[ch][n] = ms * cos_rev(rv);
        stpi[ch][n] = ms * sin_rev(rv);
    }
    __syncthreads();

    float xr[16], xi[16];
    #pragma unroll
    for (int j = 0; j < 16; ++j) { xr[j] = 0.0f; xi[j] = 0.0f; }

    float tf = (float)t;
    #pragma unroll
    for (int ch = 0; ch < 2; ++ch) {
        for (int n = 0; n < NS_; ++n) {
            float trv = thrv[ch][n], l2 = lnr2[ch][n];
            float f = trv * tf; f -= floorf(f);
            float mag = __builtin_exp2f(l2 * tf);
            float vr = mag * cos_rev(f);
            float vi = mag * sin_rev(f);
            float sr = stpr[ch][n], si = stpi[ch][n];
            float cr = ctr[ch][n],  ci = cti[ch][n];
            #pragma unroll
            for (int j = 0; j < 8; ++j) {
                float contrib = cr*vr - ci*vi;
                if (ch == 0) xr[j] += contrib; else xi[j] += contrib;
                float nvr = vr*sr - vi*si;
                vi = vr*si + vi*sr;
                vr = nvr;
            }
        }
    }
    #pragma unroll
    for (int j = 0; j < 8; ++j) { xr[j] *= 2.0f; xi[j] *= 2.0f; }

    fft4096_fwd_reg(xr, xi, lre, lim, t);

    __syncthreads();
    #pragma unroll
    for (int k = 0; k < 16; ++k) { int idx = XP(k*256 + t); lre[idx] = xr[k]; lim[idx] = xi[k]; }
    __syncthreads();

    const float scale = 1.0f / (float)N2;
    #pragma unroll
    for (int it = 0; it < 16; ++it) {
        int j = 256*it + t;
        int k = (t >> 4) + ((t & 15) << 4) + (it << 8);
        int kc = (N2 - k) & (N2 - 1);
        int j2 = ((kc >> 8) << 8) + ((kc & 15) << 4) + ((kc >> 4) & 15);
        float za = xr[it], zb = xi[it];
        float zc = lre[XP(j2)], zd = lim[XP(j2)];
        float Xr = 0.5f*(za + zc), Xi2 = 0.5f*(zb - zd);
        float Yr = 0.5f*(zb + zd), Yi = 0.5f*(zc - za);
        Kout[(size_t)hp*N2 + j] = make_float4(Xr*scale, Xi2*scale, Yr*scale, Yi*scale);
    }
}

// ---------------- kernel 3: LayerNorm + build z_t (B,H,S) with reversed half ----------------
__global__ __launch_bounds__(256) void ln_kernel(
        const float* __restrict__ x, const float* __restrict__ gamma,
        const float* __restrict__ beta, const int* __restrict__ cz,
        float* __restrict__ z_t) {
    int blk = blockIdx.x;
    int b = blk >> 6;
    int s0 = (blk & 63) * 32;
    int t = threadIdx.x;
    int lane = t & 63, wave = t >> 6;
    __shared__ float st[32][257];

    float4 g4  = *(const float4*)(gamma + lane*4);
    float4 be4 = *(const float4*)(beta  + lane*4);
    for (int q = 0; q < 8; ++q) {
        int row = wave*8 + q;
        int s = s0 + row;
        float4 v = *(const float4*)(x + ((size_t)(b*S_ + s))*D_ + lane*4);
        float sum = v.x + v.y + v.z + v.w;
        float ss  = v.x*v.x + v.y*v.y + v.z*v.z + v.w*v.w;
        for (int off = 32; off; off >>= 1) {
            sum += __shfl_xor(sum, off);
            ss  += __shfl_xor(ss, off);
        }
        float mean = sum * (1.0f/(float)D_);
        float var  = ss  * (1.0f/(float)D_) - mean*mean;
        float rstd = rsqrtf(var + 1e-5f);
        st[row][lane*4+0] = (v.x - mean)*rstd*g4.x + be4.x;
        st[row][lane*4+1] = (v.y - mean)*rstd*g4.y + be4.y;
        st[row][lane*4+2] = (v.z - mean)*rstd*g4.z + be4.z;
        st[row][lane*4+3] = (v.w - mean)*rstd*g4.w + be4.w;
    }
    __syncthreads();
    int czb = cz[b];
    int s_off = t & 31, dg = t >> 5;
    int s = s0 + s_off;
    int bs = (2*S_ - 1 - czb - s) % S_;
    for (int i = 0; i < 32; ++i) {
        int d = dg + 8*i;
        float v = st[s_off][d];
        z_t[((size_t)(b*H_ + d      ))*S_ + s ] = v;
        z_t[((size_t)(b*H_ + D_ + d ))*S_ + bs] = v;
    }
}

// ---------------- kernel 4: packed FFT conv + D_skip + gelu -> bf16 (in place) ----------------
__global__ __launch_bounds__(256) void fftconv_kernel(
        const float* __restrict__ z_t, const float4* __restrict__ Kf4,
        const float* __restrict__ D_skip, unsigned short* __restrict__ ybf) {
    int blk = blockIdx.x;
    int b  = blk >> 8;
    int hp = blk & 255;
    int h0 = hp * 2;
    int t = threadIdx.x;
    __shared__ float lre[N2 + N2/16];
    __shared__ float lim[N2 + N2/16];

    const float* zrow1 = z_t + ((size_t)(b*H_ + h0    ))*S_;
    const float* zrow2 = z_t + ((size_t)(b*H_ + h0 + 1))*S_;
    float xr[16], xi[16];
    float z1r[8], z2r[8];
    #pragma unroll
    for (int j = 0; j < 8; ++j) {
        int s = t + 256*j;
        float v1 = zrow1[s], v2 = zrow2[s];
        z1r[j] = v1; z2r[j] = v2;
        xr[j] = v1;  xi[j] = v2;
        xr[j+8] = 0.0f; xi[j+8] = 0.0f;
    }

    fft4096_fwd_reg(xr, xi, lre, lim, t);

    __syncthreads();
    #pragma unroll
    for (int k = 0; k < 16; ++k) { int idx = XP(k*256 + t); lre[idx] = xr[k]; lim[idx] = xi[k]; }
    __syncthreads();

    const float4* kp = Kf4 + (size_t)hp * N2;
    #pragma unroll
    for (int it = 0; it < 16; ++it) {
        int j = 256*it + t;
        int k = (t >> 4) + ((t & 15) << 4) + (it << 8);
        int kc = (N2 - k) & (N2 - 1);
        int j2 = ((kc >> 8) << 8) + ((kc & 15) << 4) + ((kc >> 4) & 15);
        float za = xr[it], zb = xi[it];
        float zc = lre[XP(j2)], zd = lim[XP(j2)];
        float Xr = 0.5f*(za + zc), Xi2 = 0.5f*(zb - zd);
        float Yr = 0.5f*(zb + zd), Yi = 0.5f*(zc - za);
        float4 kk = kp[j];
        float Pr = Xr*kk.x - Xi2*kk.y, Pi = Xr*kk.y + Xi2*kk.x;
        float Qr = Yr*kk.z - Yi*kk.w,  Qi = Yr*kk.w + Yi*kk.z;
        xr[it] = Pr - Qi;
        xi[it] = Pi + Qr;
    }

    fft4096_inv_reg(xr, xi, lre, lim, t);

    float dsk1 = D_skip[h0], dsk2 = D_skip[h0+1];
    unsigned short* yb1 = ybf + ((size_t)(b*H_ + h0    ))*2*S_;
    unsigned short* yb2 = ybf + ((size_t)(b*H_ + h0 + 1))*2*S_;
    #pragma unroll
    for (int j = 0; j < 8; ++j) {
        int s = t + 256*j;
        float y1 = xr[j] + dsk1 * z1r[j];
        float y2 = xi[j] + dsk2 * z2r[j];
        yb1[s] = f2bf(gelu_f(y1));
        yb2[s] = f2bf(gelu_f(y2));
    }
}

// ---------------- kernel 5: (B,H,2S)bf16 rows -> (B,S,H) bf16 with back-half re-reversal ----------------
__global__ __launch_bounds__(256) void transpose_kernel(
        const unsigned short* __restrict__ ybf, const int* __restrict__ cz,
        unsigned short* __restrict__ A) {
    int b  = blockIdx.z;
    int h0 = blockIdx.y * 64;
    int s0 = blockIdx.x * 64;
    int t = threadIdx.x;
    int tx = t & 63, ty = t >> 6;
    __shared__ unsigned short tile[64][65];
    bool back = (h0 >= D_);
    int czb = cz[b];
    int s = s0 + tx;
    int scol = back ? ((2*S_ - 1 - czb - s) % S_) : s;
    for (int i = 0; i < 16; ++i) {
        int hh = ty*16 + i;
        tile[hh][tx] = ybf[((size_t)(b*H_ + h0 + hh))*2*S_ + scol];
    }
    __syncthreads();
    for (int i = 0; i < 16; ++i) {
        int sl = ty*16 + i;
        A[((size_t)(b*S_ + s0 + sl))*H_ + h0 + tx] = tile[tx][sl];
    }
}

// ---------------- kernel 6: GLU GEMM, 128x256 tile, global_load_lds, swizzled LDS ----------------
__global__ __launch_bounds__(256) void glu_gemm_kernel(
        const unsigned short* __restrict__ A, const unsigned short* __restrict__ Wt,
        const float* __restrict__ bglu, const float* __restrict__ x,
        float* __restrict__ out) {
    int m0 = blockIdx.x * 128;
    int nh = blockIdx.y;              // which 128 d-cols
    int t = threadIdx.x;
    int lane = t & 63, w = t >> 6;
    __shared__ __align__(16) unsigned short Ab[2][4096];   // 128 rows x 32 k (swizzled)
    __shared__ __align__(16) unsigned short Bb[2][8192];   // 256 rows x 32 k (swizzled)

    f32x4 acc[2][16];
    #pragma unroll
    for (int mf = 0; mf < 2; ++mf)
        #pragma unroll
        for (int nf = 0; nf < 16; ++nf)
            acc[mf][nf] = (f32x4){0.0f, 0.0f, 0.0f, 0.0f};

    int r = t >> 2;                 // 0..63 (row within 64-row staging group)
    int kch = (t & 3) * 8;          // k-element chunk base
    int wbase = (t >> 6) * 1024;    // wave-uniform LDS byte offset within 4KB instr region

    auto stage = [&](int buf, int kk) {
        #pragma unroll
        for (int i = 0; i < 2; ++i) {
            int row = i*64 + r;
            int kel = kch ^ (((row >> 2) & 3) << 3);
            const unsigned short* src = A + ((size_t)(m0 + row))*H_ + kk + kel;
            char* dst = (char*)&Ab[buf][0] + i*4096 + wbase;
            __builtin_amdgcn_global_load_lds((const __attribute__((address_space(1))) void*)src,
                                             (__attribute__((address_space(3))) void*)dst, 16, 0, 0);
        }
        #pragma unroll
        for (int i = 0; i < 4; ++i) {
            int rb = i*64 + r;
            int n = nh*128 + rb + (rb & 128);   // rows 0-127 -> a-cols, 128-255 -> b-cols
            int kel = kch ^ (((rb >> 2) & 3) << 3);
            const unsigned short* src = Wt + ((size_t)n)*H_ + kk + kel;
            char* dst = (char*)&Bb[buf][0] + i*4096 + wbase;
            __builtin_amdgcn_global_load_lds((const __attribute__((address_space(1))) void*)src,
                                             (__attribute__((address_space(3))) void*)dst, 16, 0, 0);
        }
    };

    int lr = lane & 15, ksel = lane >> 4;
    stage(0, 0);
    __syncthreads();

    #pragma unroll 1
    for (int step = 0; step < 16; ++step) {
        int cur = step & 1;
        if (step < 15) stage(cur ^ 1, (step + 1) * 32);
        const char* pa = (const char*)&Ab[cur][0];
        const char* pb = (const char*)&Bb[cur][0];
        bf16x8 af[2];
        #pragma unroll
        for (int mf = 0; mf < 2; ++mf) {
            int arow = w*32 + mf*16 + lr;
            af[mf] = *(const bf16x8*)(pa + arow*64 + ((ksel*16) ^ (((arow >> 2) & 3) << 4)));
        }
        #pragma unroll
        for (int nf = 0; nf < 16; ++nf) {
            int brow = nf*16 + lr;
            bf16x8 bv = *(const bf16x8*)(pb + brow*64 + ((ksel*16) ^ (((brow >> 2) & 3) << 4)));
            acc[0][nf] = __builtin_amdgcn_mfma_f32_16x16x32_bf16(af[0], bv, acc[0][nf], 0, 0, 0);
            acc[1][nf] = __builtin_amdgcn_mfma_f32_16x16x32_bf16(af[1], bv, acc[1][nf], 0, 0, 0);
        }
        __syncthreads();
    }

    // epilogue: a at nf, paired b at nf+8 (register-local)
    int r4 = (lane >> 4) * 4;
    #pragma unroll
    for (int mf = 0; mf < 2; ++mf) {
        #pragma unroll
        for (int nf = 0; nf < 8; ++nf) {
            int tc = nf*16 + lr;
            int dcol = nh*128 + tc;
            float ba = bglu[dcol];
            float bb = bglu[256 + dcol];
            #pragma unroll
            for (int rr = 0; rr < 4; ++rr) {
                int row = w*32 + mf*16 + r4 + rr;
                size_t mi = (size_t)(m0 + row);
                float av = acc[mf][nf][rr] + ba;
                float bv = acc[mf][nf+8][rr] + bb;
                float sig = 1.0f / (1.0f + __builtin_exp2f(-1.4426950408889634f * bv));
                out[mi*D_ + dcol] = av*sig + x[mi*D_ + dcol];
            }
        }
    }
}

// ---------------- launch ----------------
extern "C" void kernel_launch(void* const* d_in, const int* in_sizes, int n_in,
                              void* d_out, int out_size, void* d_ws, size_t ws_size,
                              hipStream_t stream) {
    const float* x         = (const float*)d_in[0];
    const float* mask      = (const float*)d_in[1];
    const float* log_dt    = (const float*)d_in[2];
    const float* log_A_real= (const float*)d_in[3];
    const float* A_imag    = (const float*)d_in[4];
    const float* B_re      = (const float*)d_in[5];
    const float* B_im      = (const float*)d_in[6];
    const float* C_re      = (const float*)d_in[7];
    const float* C_im      = (const float*)d_in[8];
    const float* D_skip    = (const float*)d_in[9];
    const float* W_glu     = (const float*)d_in[10];
    const float* b_glu     = (const float*)d_in[11];
    const float* ln_gamma  = (const float*)d_in[12];
    const float* ln_beta   = (const float*)d_in[13];
    float* out = (float*)d_out;

    char* ws = (char*)d_ws;
    int*            cz  = (int*)ws;
    float*          z_t = (float*)(ws + 256);
    float4*         Kf  = (float4*)(ws + 256 + 67108864);
    unsigned short* Abf = (unsigned short*)(ws + 256 + 67108864 + 16777216);
    unsigned short* Wt  = (unsigned short*)(ws + 256 + 67108864 + 16777216 + 33554432);
    unsigned short* ybf = (unsigned short*)z_t;

    count_kernel<<<B_, 256, 0, stream>>>(mask, cz);
    wprep_kernel<<<(H_*H_)/256, 256, 0, stream>>>(W_glu, Wt);
    kfft_kernel<<<H_/2, 256, 0, stream>>>(log_dt, log_A_real, A_imag, B_re, B_im, C_re, C_im, Kf);
    ln_kernel<<<B_*(S_/32), 256, 0, stream>>>(x, ln_gamma, ln_beta, cz, z_t);
    fftconv_kernel<<<B_*(H_/2), 256, 0, stream>>>(z_t, (const float4*)Kf, D_skip, ybf);
    transpose_kernel<<<dim3(S_/64, H_/64, B_), 256, 0, stream>>>(ybf, cz, Abf);
    glu_gemm_kernel<<<dim3(M_/128, 2), 256, 0, stream>>>(Abf, Wt, b_glu, x, out);
}